// Round 4
// baseline (4708.191 us; speedup 1.0000x reference)
//
#include <hip/hip_runtime.h>
#include <hip/hip_bf16.h>
#include <math.h>

// LearnablePQ round 2 (second resubmit — rounds 2 and 3 both hit
// GPUAcquisitionTimeout; this kernel has never executed):
// full-f64-accuracy fused pipeline.
// Rationale: output = codebook rows selected by argmin over 1M decisions;
// threshold (2% of max) allows ZERO argmin flips vs the np reference. Any
// independent f32 pipeline carries ~1e-6 relative noise -> expected ~10-50
// flips (observed 0.18 absmax in round 1). f64 end-to-end gives ~1e-13 noise
// -> expected flips ~4e-6. GEMM accumulate f64, gelu via erf(double),
// h1/h2/encoded stored f64 in LDS, PQ distances+argmin f64, output bit-exact
// f32 codebook copy.

#define IN_DIM 768
#define HD1    512
#define HD2    384
#define TGT    256
#define NSUB   16
#define KCODE  256
#define SUBD   16
#define RPB    8     // rows per block (f64 LDS: 8*512*8 + 8*384*8 = 56 KB)
#define NT     256

__device__ __forceinline__ double gelu64(double v) {
    return 0.5 * v * (1.0 + erf(v * 0.70710678118654752440084436210485));
}

__global__ __launch_bounds__(NT) void fused_mlp_pq_f64(
    const float* __restrict__ x,
    const float* __restrict__ W1, const float* __restrict__ b1,
    const float* __restrict__ W2, const float* __restrict__ b2,
    const float* __restrict__ W3, const float* __restrict__ b3,
    const float* __restrict__ cbs,
    float* __restrict__ out)
{
    // LDS (f64): h1 [8][512] = 32KB @ 0; h2 [8][384] = 24KB @ 32KB.
    // enc [8][256] f64 = 16KB aliases h1 (h1 dead after GEMM2's reads, and
    // enc writes happen after the post-GEMM2 barrier).
    __shared__ double lds[RPB * HD1 + RPB * HD2];   // 7168 doubles = 56 KB
    double* h1s  = lds;
    double* h2s  = lds + RPB * HD1;
    double* encs = lds;   // alias over h1 region

    const int t = threadIdx.x;
    const size_t row0 = (size_t)blockIdx.x * RPB;

    // ---------- GEMM1: (8x768)@(768x512)+b1, gelu -> h1s (f64) ----------
    // rg = t>>7 (2 groups x 4 rows), cg = t&127 (x 4 cols)
    {
        const int rg = t >> 7, cg = t & 127;
        const int c0 = cg << 2;
        const int r0 = rg << 2;
        double acc[4][4];
        #pragma unroll
        for (int j = 0; j < 4; ++j)
            #pragma unroll
            for (int c = 0; c < 4; ++c) acc[j][c] = 0.0;

        const float* xr0 = x + (row0 + r0) * IN_DIM;
        const float* xr1 = xr0 + IN_DIM;
        const float* xr2 = xr1 + IN_DIM;
        const float* xr3 = xr2 + IN_DIM;
        const float* wp  = W1 + c0;

        for (int k = 0; k < IN_DIM; k += 4) {
            float4 a0 = *(const float4*)(xr0 + k);
            float4 a1 = *(const float4*)(xr1 + k);
            float4 a2 = *(const float4*)(xr2 + k);
            float4 a3 = *(const float4*)(xr3 + k);
            #pragma unroll
            for (int kk = 0; kk < 4; ++kk) {
                float4 w = *(const float4*)(wp);
                wp += HD1;
                double w0 = (double)w.x, w1 = (double)w.y;
                double w2 = (double)w.z, w3 = (double)w.w;
                double av0 = (double)((const float*)&a0)[kk];
                double av1 = (double)((const float*)&a1)[kk];
                double av2 = (double)((const float*)&a2)[kk];
                double av3 = (double)((const float*)&a3)[kk];
                acc[0][0] = fma(av0, w0, acc[0][0]); acc[0][1] = fma(av0, w1, acc[0][1]);
                acc[0][2] = fma(av0, w2, acc[0][2]); acc[0][3] = fma(av0, w3, acc[0][3]);
                acc[1][0] = fma(av1, w0, acc[1][0]); acc[1][1] = fma(av1, w1, acc[1][1]);
                acc[1][2] = fma(av1, w2, acc[1][2]); acc[1][3] = fma(av1, w3, acc[1][3]);
                acc[2][0] = fma(av2, w0, acc[2][0]); acc[2][1] = fma(av2, w1, acc[2][1]);
                acc[2][2] = fma(av2, w2, acc[2][2]); acc[2][3] = fma(av2, w3, acc[2][3]);
                acc[3][0] = fma(av3, w0, acc[3][0]); acc[3][1] = fma(av3, w1, acc[3][1]);
                acc[3][2] = fma(av3, w2, acc[3][2]); acc[3][3] = fma(av3, w3, acc[3][3]);
            }
        }
        double bb[4];
        #pragma unroll
        for (int c = 0; c < 4; ++c) bb[c] = (double)b1[c0 + c];
        #pragma unroll
        for (int j = 0; j < 4; ++j)
            #pragma unroll
            for (int c = 0; c < 4; ++c)
                h1s[(r0 + j) * HD1 + c0 + c] = gelu64(acc[j][c] + bb[c]);
    }
    __syncthreads();

    // ---------- GEMM2: (8x512)@(512x384)+b2, gelu -> h2s (f64) ----------
    // rg = t>>7 (x 4 rows), cg = t&127 (x 3 cols)
    {
        const int rg = t >> 7, cg = t & 127;
        const int c0 = cg * 3;
        const int r0 = rg << 2;
        double acc[4][3];
        #pragma unroll
        for (int j = 0; j < 4; ++j)
            #pragma unroll
            for (int c = 0; c < 3; ++c) acc[j][c] = 0.0;

        const double* hr0 = h1s + r0 * HD1;
        const double* hr1 = hr0 + HD1;
        const double* hr2 = hr1 + HD1;
        const double* hr3 = hr2 + HD1;
        const float* wp = W2 + c0;

        for (int k = 0; k < HD1; k += 2) {
            double2 a0 = *(const double2*)(hr0 + k);
            double2 a1 = *(const double2*)(hr1 + k);
            double2 a2 = *(const double2*)(hr2 + k);
            double2 a3 = *(const double2*)(hr3 + k);
            #pragma unroll
            for (int kk = 0; kk < 2; ++kk) {
                double w0 = (double)wp[0];
                double w1 = (double)wp[1];
                double w2 = (double)wp[2];
                wp += HD2;
                double av0 = kk ? a0.y : a0.x;
                double av1 = kk ? a1.y : a1.x;
                double av2 = kk ? a2.y : a2.x;
                double av3 = kk ? a3.y : a3.x;
                acc[0][0] = fma(av0, w0, acc[0][0]); acc[0][1] = fma(av0, w1, acc[0][1]); acc[0][2] = fma(av0, w2, acc[0][2]);
                acc[1][0] = fma(av1, w0, acc[1][0]); acc[1][1] = fma(av1, w1, acc[1][1]); acc[1][2] = fma(av1, w2, acc[1][2]);
                acc[2][0] = fma(av2, w0, acc[2][0]); acc[2][1] = fma(av2, w1, acc[2][1]); acc[2][2] = fma(av2, w2, acc[2][2]);
                acc[3][0] = fma(av3, w0, acc[3][0]); acc[3][1] = fma(av3, w1, acc[3][1]); acc[3][2] = fma(av3, w2, acc[3][2]);
            }
        }
        double bb[3];
        #pragma unroll
        for (int c = 0; c < 3; ++c) bb[c] = (double)b2[c0 + c];
        #pragma unroll
        for (int j = 0; j < 4; ++j)
            #pragma unroll
            for (int c = 0; c < 3; ++c)
                h2s[(r0 + j) * HD2 + c0 + c] = gelu64(acc[j][c] + bb[c]);
    }
    __syncthreads();

    // ---------- GEMM3: (8x384)@(384x256)+b3 -> encs (f64, aliases h1) ----------
    // rg = t>>7 (x 4 rows), cg = t&127 (x 2 cols)
    {
        const int rg = t >> 7, cg = t & 127;
        const int c0 = cg << 1;
        const int r0 = rg << 2;
        double acc[4][2];
        #pragma unroll
        for (int j = 0; j < 4; ++j)
            #pragma unroll
            for (int c = 0; c < 2; ++c) acc[j][c] = 0.0;

        const double* hr0 = h2s + r0 * HD2;
        const double* hr1 = hr0 + HD2;
        const double* hr2 = hr1 + HD2;
        const double* hr3 = hr2 + HD2;
        const float* wp = W3 + c0;

        for (int k = 0; k < HD2; k += 2) {
            double2 a0 = *(const double2*)(hr0 + k);
            double2 a1 = *(const double2*)(hr1 + k);
            double2 a2 = *(const double2*)(hr2 + k);
            double2 a3 = *(const double2*)(hr3 + k);
            #pragma unroll
            for (int kk = 0; kk < 2; ++kk) {
                double w0 = (double)wp[0];
                double w1 = (double)wp[1];
                wp += TGT;
                double av0 = kk ? a0.y : a0.x;
                double av1 = kk ? a1.y : a1.x;
                double av2 = kk ? a2.y : a2.x;
                double av3 = kk ? a3.y : a3.x;
                acc[0][0] = fma(av0, w0, acc[0][0]); acc[0][1] = fma(av0, w1, acc[0][1]);
                acc[1][0] = fma(av1, w0, acc[1][0]); acc[1][1] = fma(av1, w1, acc[1][1]);
                acc[2][0] = fma(av2, w0, acc[2][0]); acc[2][1] = fma(av2, w1, acc[2][1]);
                acc[3][0] = fma(av3, w0, acc[3][0]); acc[3][1] = fma(av3, w1, acc[3][1]);
            }
        }
        double bb[2];
        #pragma unroll
        for (int c = 0; c < 2; ++c) bb[c] = (double)b3[c0 + c];
        #pragma unroll
        for (int j = 0; j < 4; ++j)
            #pragma unroll
            for (int c = 0; c < 2; ++c)
                encs[(r0 + j) * TGT + c0 + c] = acc[j][c] + bb[c];
    }
    __syncthreads();

    // ---------- PQ: f64 argmin over 256 codes, split-k across lane pairs ----------
    // t: r = t>>5 (8 rows), s = (t>>1)&15 (16 subs), half = t&1 (codes 0-127 / 128-255)
    {
        const int r = t >> 5;
        const int s = (t >> 1) & 15;
        const int half = t & 1;

        double e[16];
        const double* ep = encs + r * TGT + s * SUBD;
        #pragma unroll
        for (int d = 0; d < 16; ++d) e[d] = ep[d];

        const float* cbS = cbs + (size_t)s * KCODE * SUBD;
        const float* cbH = cbS + half * 128 * SUBD;

        double best = 1.0e300;
        int bi = 0;
        for (int kk = 0; kk < 128; ++kk) {
            const float4* cp = (const float4*)(cbH + kk * SUBD);
            float4 c0 = cp[0], c1 = cp[1], c2 = cp[2], c3 = cp[3];
            double dist = 0.0;
            double dd;
            dd = (double)c0.x - e[0];  dist = fma(dd, dd, dist);
            dd = (double)c0.y - e[1];  dist = fma(dd, dd, dist);
            dd = (double)c0.z - e[2];  dist = fma(dd, dd, dist);
            dd = (double)c0.w - e[3];  dist = fma(dd, dd, dist);
            dd = (double)c1.x - e[4];  dist = fma(dd, dd, dist);
            dd = (double)c1.y - e[5];  dist = fma(dd, dd, dist);
            dd = (double)c1.z - e[6];  dist = fma(dd, dd, dist);
            dd = (double)c1.w - e[7];  dist = fma(dd, dd, dist);
            dd = (double)c2.x - e[8];  dist = fma(dd, dd, dist);
            dd = (double)c2.y - e[9];  dist = fma(dd, dd, dist);
            dd = (double)c2.z - e[10]; dist = fma(dd, dd, dist);
            dd = (double)c2.w - e[11]; dist = fma(dd, dd, dist);
            dd = (double)c3.x - e[12]; dist = fma(dd, dd, dist);
            dd = (double)c3.y - e[13]; dist = fma(dd, dd, dist);
            dd = (double)c3.z - e[14]; dist = fma(dd, dd, dist);
            dd = (double)c3.w - e[15]; dist = fma(dd, dd, dist);
            if (dist < best) { best = dist; bi = kk; }
        }
        bi += half * 128;

        // combine with the pair lane (t^1, same wave). First-index tie-break:
        // half0 owns k<128, so on exact tie prefer the smaller index.
        double obest = __shfl_xor(best, 1);
        int    obi   = __shfl_xor(bi, 1);
        if (obest < best || (obest == best && obi < bi)) { best = obest; bi = obi; }

        // both lanes of the pair agree; each writes 8 of the 16 floats
        const float4* sp = (const float4*)(cbS + bi * SUBD);
        float* op = out + (row0 + r) * TGT + s * SUBD;
        if (half == 0) {
            ((float4*)op)[0] = sp[0];
            ((float4*)op)[1] = sp[1];
        } else {
            ((float4*)op)[2] = sp[2];
            ((float4*)op)[3] = sp[3];
        }
    }
}

extern "C" void kernel_launch(void* const* d_in, const int* in_sizes, int n_in,
                              void* d_out, int out_size, void* d_ws, size_t ws_size,
                              hipStream_t stream) {
    const float* x   = (const float*)d_in[0];
    const float* W1  = (const float*)d_in[1];
    const float* b1  = (const float*)d_in[2];
    const float* W2  = (const float*)d_in[3];
    const float* b2  = (const float*)d_in[4];
    const float* W3  = (const float*)d_in[5];
    const float* b3  = (const float*)d_in[6];
    const float* cbs = (const float*)d_in[7];
    float* out = (float*)d_out;

    const int B = in_sizes[0] / IN_DIM;   // 65536
    dim3 grid(B / RPB), block(NT);
    hipLaunchKernelGGL(fused_mlp_pq_f64, grid, block, 0, stream,
                       x, W1, b1, W2, b2, W3, b3, cbs, out);
}